// Round 1
// baseline (461.275 us; speedup 1.0000x reference)
//
#include <hip/hip_runtime.h>
#include <math.h>

// Problem constants (B=8, H=8, S=16384, Dv=64, d_k=1)
#define S_LEN 16384
#define DV    64
#define NBH   64            // B*H
#define NBLK  16            // stage-1 blocks per (b,h)
#define CHUNK (S_LEN / NBLK) // 1024 rows per stage-1 block

// out[b,h,s,e] = Q[s] * (sum_s K[s]*V[s,e]) / (||Q|| * ||K||)   per (b,h)

// ---------------- Stage 1: partial ktv over a chunk of S ----------------
// grid = NBH*NBLK blocks, 256 threads.
// Thread layout: e4 = tid & 15 (float4 column), sg = tid >> 4 (16 s-groups).
__global__ __launch_bounds__(256) void stage1_partial_ktv(
    const float* __restrict__ K, const float* __restrict__ V,
    float* __restrict__ partial) {
    const int bh  = blockIdx.x >> 4;
    const int blk = blockIdx.x & 15;
    const int tid = threadIdx.x;
    const int e4  = tid & 15;
    const int sg  = tid >> 4;

    const float*  Kb = K + (size_t)bh * S_LEN;
    const float4* Vb = (const float4*)(V + (size_t)bh * S_LEN * DV);

    const int s0 = blk * CHUNK;
    float4 acc = make_float4(0.f, 0.f, 0.f, 0.f);
    #pragma unroll 4
    for (int i = 0; i < CHUNK / 16; ++i) {
        const int s = s0 + i * 16 + sg;
        const float  k = Kb[s];                      // broadcast per 16 lanes
        const float4 v = Vb[(size_t)s * 16 + e4];    // coalesced 256B/quarter-wave
        acc.x += k * v.x; acc.y += k * v.y;
        acc.z += k * v.z; acc.w += k * v.w;
    }

    __shared__ float4 red[16][16];   // [sg][e4]
    red[sg][e4] = acc;
    __syncthreads();

    if (tid < DV) {                  // tid = e in [0,64)
        const float* base = (const float*)red;
        float s = 0.f;
        #pragma unroll
        for (int p = 0; p < 16; ++p) s += base[p * DV + tid];
        partial[((size_t)bh * NBLK + blk) * DV + tid] = s;
    }
}

// ---------------- Stage 2: norms + finalize fk table ----------------
// grid = NBH blocks, 256 threads. fk[bh][e] = ktv[e] / (||Q||*||K||)
__global__ __launch_bounds__(256) void stage2_finalize(
    const float* __restrict__ Q, const float* __restrict__ K,
    const float* __restrict__ partial, float* __restrict__ fk) {
    const int bh  = blockIdx.x;
    const int tid = threadIdx.x;

    const float4* Q4 = (const float4*)(Q + (size_t)bh * S_LEN);
    const float4* K4 = (const float4*)(K + (size_t)bh * S_LEN);

    float qss = 0.f, kss = 0.f;
    for (int i = tid; i < S_LEN / 4; i += 256) {
        const float4 q = Q4[i];
        const float4 k = K4[i];
        qss += q.x * q.x + q.y * q.y + q.z * q.z + q.w * q.w;
        kss += k.x * k.x + k.y * k.y + k.z * k.z + k.w * k.w;
    }

    __shared__ float rq[256], rk[256];
    rq[tid] = qss; rk[tid] = kss;
    __syncthreads();
    #pragma unroll
    for (int off = 128; off > 0; off >>= 1) {
        if (tid < off) { rq[tid] += rq[tid + off]; rk[tid] += rk[tid + off]; }
        __syncthreads();
    }

    __shared__ float inv_norm;
    if (tid == 0) inv_norm = 1.0f / (sqrtf(rq[0]) * sqrtf(rk[0]));
    __syncthreads();

    if (tid < DV) {
        float s = 0.f;
        #pragma unroll
        for (int p = 0; p < NBLK; ++p)
            s += partial[((size_t)bh * NBLK + p) * DV + tid];
        fk[(size_t)bh * DV + tid] = s * inv_norm;
    }
}

// ---------------- Stage 3: rank-1 outer product write ----------------
// Flat float4 grid over the output. 16 float4 per row of 64.
__global__ __launch_bounds__(256) void stage3_outer(
    const float* __restrict__ Q, const float* __restrict__ fk,
    float4* __restrict__ out) {
    const size_t idx = (size_t)blockIdx.x * 256 + threadIdx.x;
    const int e4 = (int)(idx & 15);
    const int s  = (int)((idx >> 4) & (S_LEN - 1));
    const int bh = (int)(idx >> 18);       // 16 * 16384 float4 per head

    const float  q = Q[(size_t)bh * S_LEN + s];
    const float4 f = ((const float4*)fk)[(size_t)bh * 16 + e4];
    out[idx] = make_float4(q * f.x, q * f.y, q * f.z, q * f.w);
}

extern "C" void kernel_launch(void* const* d_in, const int* in_sizes, int n_in,
                              void* d_out, int out_size, void* d_ws, size_t ws_size,
                              hipStream_t stream) {
    const float* Q = (const float*)d_in[0];
    const float* K = (const float*)d_in[1];
    const float* V = (const float*)d_in[2];
    float* out = (float*)d_out;

    // Workspace layout: [partial: NBH*NBLK*DV floats][fk: NBH*DV floats]
    float* partial = (float*)d_ws;
    float* fk      = partial + (size_t)NBH * NBLK * DV;

    stage1_partial_ktv<<<NBH * NBLK, 256, 0, stream>>>(K, V, partial);
    stage2_finalize<<<NBH, 256, 0, stream>>>(Q, K, partial, fk);

    // total float4 in output: 8*8*16384*16 = 16,777,216 -> 65536 blocks
    const int n4 = NBH * S_LEN * (DV / 4);
    stage3_outer<<<n4 / 256, 256, 0, stream>>>(Q, fk, (float4*)out);
}